// Round 21
// baseline (2970.753 us; speedup 1.0000x reference)
//
#include <hip/hip_runtime.h>
#include <hip/hip_bf16.h>
#include <hip/hip_fp16.h>

typedef __attribute__((ext_vector_type(4))) int i32x4;
typedef __attribute__((ext_vector_type(8))) unsigned short u16x8;
typedef __attribute__((ext_vector_type(8))) char c8;
typedef __attribute__((ext_vector_type(4))) char c4;
typedef unsigned int u32;
typedef unsigned short u16;

#define SCH0() __builtin_amdgcn_sched_barrier(0)

// ---------- helpers ----------
__device__ __forceinline__ void gload_lds16(const void* g, void* l) {
  __builtin_amdgcn_global_load_lds((const u32 __attribute__((address_space(1)))*)g,
                                   (u32 __attribute__((address_space(3)))*)l, 16, 0, 0);
}
__device__ __forceinline__ float h2f(u16 u) { return __half2float(__ushort_as_half(u)); }
__device__ __forceinline__ u16  f2h(float f){ return __half_as_ushort(__float2half_rn(f)); }

// ---------- 1. FUSED prep: quant_x (blocks 0..8191) + absum w1 (8192..8703) + absum w2 (8704..9215) ----------
__global__ __launch_bounds__(256) void prep_kernel(const float* __restrict__ x,
    char* __restrict__ qx, float* __restrict__ invs,
    const float* __restrict__ w1, const float* __restrict__ w2,
    double* __restrict__ part) {
  const int tid = threadIdx.x;
  __shared__ double sd[256];
  __shared__ float sf[256];
  if (blockIdx.x < 8192) {
    const int D = 2048;
    int row = blockIdx.x;
    const float* xr = x + (size_t)row * D;
    float4 a = ((const float4*)xr)[tid * 2], b = ((const float4*)xr)[tid * 2 + 1];
    float v[8] = {a.x, a.y, a.z, a.w, b.x, b.y, b.z, b.w};
    double ss = 0; float mx = 0.0f;
#pragma unroll
    for (int i = 0; i < 8; i++) { ss += (double)v[i] * v[i]; mx = fmaxf(mx, fabsf(v[i])); }
    sd[tid] = ss; sf[tid] = mx; __syncthreads();
    for (int o = 128; o > 0; o >>= 1) {
      if (tid < o) { sd[tid] += sd[tid + o]; sf[tid] = fmaxf(sf[tid], sf[tid + o]); }
      __syncthreads();
    }
    __shared__ float bn, bs;
    if (tid == 0) {
      float n = fmaxf((float)sqrt(sd[0]), 1e-12f);
      float amax = sf[0] * (sqrtf((float)D) / n);
      float cl = fmaxf(amax, 1e-5f);
      bn = n; bs = 127.0f / cl;
      invs[row] = cl / 127.0f;
    }
    __syncthreads();
    float n = bn, s = bs, sq = sqrtf((float)D);
    c8 q;
#pragma unroll
    for (int i = 0; i < 8; i++) {
      float xn = (v[i] / n) * sq;
      float r = rintf(xn * s);
      r = fminf(fmaxf(r, -128.0f), 127.0f);
      q[i] = (char)(int)r;
    }
    *(c8*)&qx[(size_t)row * D + tid * 8] = q;
  } else {
    const int n4 = 4194304;
    const bool isw2 = blockIdx.x >= 8704;
    const float* w = isw2 ? w2 : w1;
    const int vb = blockIdx.x - (isw2 ? 8704 : 8192);
    double s = 0;
    for (int i = vb * 256 + tid; i < n4; i += 512 * 256) {
      float4 v = ((const float4*)w)[i];
      s += (double)fabsf(v.x) + (double)fabsf(v.y) + (double)fabsf(v.z) + (double)fabsf(v.w);
    }
    sd[tid] = s; __syncthreads();
    for (int o = 128; o > 0; o >>= 1) { if (tid < o) sd[tid] += sd[tid + o]; __syncthreads(); }
    if (tid == 0) part[(isw2 ? 512 : 0) + vb] = sd[0];
  }
}

__global__ __launch_bounds__(256) void wscale_final(const double* __restrict__ part,
    float* __restrict__ wsc) {
  int tid = threadIdx.x;
  __shared__ double sd[256];
  sd[tid] = part[tid] + part[tid + 256]; __syncthreads();
  for (int o = 128; o > 0; o >>= 1) { if (tid < o) sd[tid] += sd[tid + o]; __syncthreads(); }
  double s1 = sd[0]; __syncthreads();
  sd[tid] = part[512 + tid] + part[768 + tid]; __syncthreads();
  for (int o = 128; o > 0; o >>= 1) { if (tid < o) sd[tid] += sd[tid + o]; __syncthreads(); }
  if (tid == 0) {
    float m1 = (float)(s1 / 16777216.0);
    float m2 = (float)(sd[0] / 16777216.0);
    float d1 = fmaxf(m1, 1e-5f), d2 = fmaxf(m2, 1e-5f);
    wsc[0] = 1.0f / d1; wsc[1] = d1; wsc[2] = 1.0f / d2; wsc[3] = d2;
  }
}

// ---------- 2. FUSED ternary weight quant ----------
__global__ __launch_bounds__(256) void quant_w_kernel(const float* __restrict__ w1,
    char* __restrict__ q1, const float* __restrict__ w2, char* __restrict__ q2,
    const float* __restrict__ wsc) {
  const int n4 = 4194304;
  const bool isw2 = blockIdx.x >= 2048;
  const float* w = isw2 ? w2 : w1;
  char* q = isw2 ? q2 : q1;
  float s = isw2 ? wsc[2] : wsc[0];
  const int vb = blockIdx.x - (isw2 ? 2048 : 0);
  for (int i = vb * 256 + threadIdx.x; i < n4; i += 2048 * 256) {
    float4 v = ((const float4*)w)[i];
    c4 o;
    o[0] = (char)(int)(fminf(fmaxf(rintf(v.x * s), -1.0f), 1.0f));
    o[1] = (char)(int)(fminf(fmaxf(rintf(v.y * s), -1.0f), 1.0f));
    o[2] = (char)(int)(fminf(fmaxf(rintf(v.z * s), -1.0f), 1.0f));
    o[3] = (char)(int)(fminf(fmaxf(rintf(v.w * s), -1.0f), 1.0f));
    ((c4*)q)[i] = o;
  }
}

// ---------- 3. 256x256 i8 GEMM, 1024 threads, 2 buffers / 64 KiB -> 2 blocks/CU ----------
// r20's confirmed TLP lever continued: 32 waves/CU (8/SIMD). VGPR capped at 64 via
// __launch_bounds__(1024, 8). Ledger = conservative full-drain (r18-proven semantics):
//   per tile: vmcnt(0)+lgkmcnt(0)+s_barrier  ->  STAGE(t+1 -> buf^1)  ->  reads ∥ 16 MFMA.
//   WAR: stage target's readers (tile t-1) drained by this barrier's lgkm.
//   RAW: vmcnt(0) retires stage(t), issued one full tile earlier; residual latency is
//   filled by the co-resident block (cross-block TLP), which r18 (1 block/CU) lacked.
// Unroll-2 keeps buffer indices compile-time. Serpentine + XCD raster unchanged.
#define READ_A4(BUF)                                                       \
  { _Pragma("unroll") for (int f_ = 0; f_ < 4; f_++)                       \
      a[f_] = *(const i32x4*)&sm[BUF][0][(wm * 64 + f_ * 16 + llo) * 64 + koff]; }
#define READ_B4(BUF)                                                       \
  { _Pragma("unroll") for (int f_ = 0; f_ < 4; f_++)                       \
      b[f_] = *(const i32x4*)&sm[BUF][1][(wn * 64 + f_ * 16 + llo) * 64 + koff]; }
#define MMAQ16()                                                           \
  { _Pragma("unroll") for (int m_ = 0; m_ < 4; m_++)                       \
      _Pragma("unroll") for (int n_ = 0; n_ < 4; n_++)                     \
        acc[m_][n_] = __builtin_amdgcn_mfma_i32_16x16x64_i8(a[m_], b[n_],  \
                                                            acc[m_][n_], 0, 0, 0); }
#define STAGE4(BUF, KT)                                                    \
  { size_t ko_ = (size_t)(KT) * 64;                                        \
    gload_lds16(gA + ko_, &sm[BUF][0][tid * 16]);                          \
    gload_lds16(gB + ko_, &sm[BUF][1][tid * 16]); }
#define TILE2(C, T)                                                        \
  { asm volatile("s_waitcnt vmcnt(0) lgkmcnt(0)\n\ts_barrier" ::: "memory"); \
    if ((T) + 1 < NT) STAGE4(C ^ 1, (T) + 1);                              \
    SCH0();                                                                \
    READ_A4(C); READ_B4(C);                                                \
    MMAQ16();                                                              \
    SCH0(); }

// EPI==0: dequant + exact GELU -> f16 store.  EPI==1: dequant -> f32 store.
template <int EPI>
__global__ __launch_bounds__(1024, 8) void gemm_i8(const char* __restrict__ A,
    const char* __restrict__ B, int N, int K, size_t ldA, size_t ldB, int gridN,
    const float* __restrict__ rowscale, const float* __restrict__ wsc,
    int widx, void* __restrict__ outp) {
  __shared__ __align__(16) char sm[2][2][16384];   // [buf][mat][256 rows x 64 B] = 64 KiB
  const int tid = threadIdx.x;
  const int lane = tid & 63, w = tid >> 6;
  const int wm = w >> 2, wn = w & 3;               // 4M x 4N wave grid, per-wave 64x64
  const int llo = lane & 15, lhi = lane >> 4;
  const int koff = ((lhi ^ ((llo >> 1) & 3)) << 4); // read-side swizzle key (row>>1)&3

  // T1: bijective XCD swizzle + group-4-row serpentine
  const int nwg = gridDim.x, cpx = nwg >> 3;
  const int swz = (blockIdx.x & 7) * cpx + (blockIdx.x >> 3);
  const int band = gridN << 2;
  const int g = swz / band, idx = swz % band;
  const int bm = (g << 2) + (idx & 3), bn = idx >> 2;

  const int NT = K >> 6;                           // 32 or 128 (even)

  // staging: thread covers one 16B slot per mat per tile (1024 slots = 256 rows x 64 B)
  // row = tid>>2, kb = tid&3; source kb' = kb ^ ((row>>1)&3) = kb ^ ((tid>>3)&3)
  const int rs = tid >> 2;
  const int kbs = (((tid & 3) ^ ((tid >> 3) & 3)) << 4);
  const char* gA = A + (size_t)(bm * 256 + rs) * ldA + kbs;
  const char* gB = B + (size_t)(bn * 256 + rs) * ldB + kbs;

  i32x4 a[4], b[4];
  i32x4 acc[4][4];
#pragma unroll
  for (int m = 0; m < 4; m++)
#pragma unroll
    for (int n = 0; n < 4; n++) acc[m][n] = (i32x4){0, 0, 0, 0};

  // prologue: tile0 -> buf0; tile 0's entry barrier drains it
  STAGE4(0, 0);

  for (int t = 0; t < NT; t += 2) {
    TILE2(0, t);
    TILE2(1, t + 1);
  }

  // ---- epilogue (i32 -> f32 exact, |acc| << 2^24)
  float wdeq = wsc[widx];
#pragma unroll
  for (int mf = 0; mf < 4; mf++) {
#pragma unroll
    for (int reg = 0; reg < 4; reg++) {
      int r = bm * 256 + wm * 64 + mf * 16 + lhi * 4 + reg;
      float deq = rowscale[r] * wdeq;
#pragma unroll
      for (int nf = 0; nf < 4; nf++) {
        int c = bn * 256 + wn * 64 + nf * 16 + llo;
        float val = (float)acc[mf][nf][reg] * deq;
        if (EPI == 0) {
          float gg = 0.5f * val * (1.0f + erff(val * 0.70710678118654752440f));
          ((u16*)outp)[(size_t)r * N + c] = f2h(gg);
        } else {
          ((float*)outp)[(size_t)r * N + c] = val;
        }
      }
    }
  }
}

// ---------- 4. per-row norm + quant of h: f16 in, i8 out IN-PLACE ----------
__global__ __launch_bounds__(256) void quant_h_kernel(u16* __restrict__ h, float* __restrict__ invs) {
  const int D = 8192;
  int row = blockIdx.x, tid = threadIdx.x;
  u16* hr = h + (size_t)row * D;
  float v[32];
#pragma unroll
  for (int j = 0; j < 4; j++) {
    u16x8 u = *(const u16x8*)&hr[j * 2048 + tid * 8];
#pragma unroll
    for (int e = 0; e < 8; e++) v[j * 8 + e] = h2f(u[e]);
  }
  double ss = 0; float mx = 0.0f;
#pragma unroll
  for (int i = 0; i < 32; i++) { ss += (double)v[i] * v[i]; mx = fmaxf(mx, fabsf(v[i])); }
  __shared__ double sd[256]; __shared__ float sf[256];
  sd[tid] = ss; sf[tid] = mx; __syncthreads();
  for (int o = 128; o > 0; o >>= 1) {
    if (tid < o) { sd[tid] += sd[tid + o]; sf[tid] = fmaxf(sf[tid], sf[tid + o]); }
    __syncthreads();
  }
  __shared__ float bn, bs;
  if (tid == 0) {
    float n = fmaxf((float)sqrt(sd[0]), 1e-12f);
    float amax = sf[0] * (sqrtf((float)D) / n);
    float cl = fmaxf(amax, 1e-5f);
    bn = n; bs = 127.0f / cl;
    invs[row] = cl / 127.0f;
  }
  __syncthreads();
  float n = bn, s = bs, sq = sqrtf((float)D);
  char* hq = (char*)hr;
#pragma unroll
  for (int j = 0; j < 4; j++) {
    c8 q;
#pragma unroll
    for (int e = 0; e < 8; e++) {
      float xn = (v[j * 8 + e] / n) * sq;
      float r = rintf(xn * s);
      r = fminf(fmaxf(r, -128.0f), 127.0f);
      q[e] = (char)(int)r;
    }
    *(c8*)&hq[j * 2048 + tid * 8] = q;
  }
}

// ---------- launch ----------
extern "C" void kernel_launch(void* const* d_in, const int* in_sizes, int n_in,
                              void* d_out, int out_size, void* d_ws, size_t ws_size,
                              hipStream_t stream) {
  const float* x  = (const float*)d_in[0];   // [4,2048,2048] f32
  const float* w1 = (const float*)d_in[1];   // [8192,2048]   f32
  const float* w2 = (const float*)d_in[2];   // [2048,8192]   f32

  char* ws = (char*)d_ws;
  char*   qx     = (char*)(ws + 0);            // 8192x2048 i8
  char*   w1q    = (char*)(ws + 16777216);     // 8192x2048 i8
  char*   w2q    = (char*)(ws + 33554432);     // 2048x8192 i8
  u16*    h      = (u16*)(ws + 50331648);      // 8192x8192 f16; i8 in-place after quant
  float*  invs_x = (float*)(ws + 184549376);
  float*  invs_h = (float*)(ws + 184582144);
  double* part   = (double*)(ws + 184614912);
  float*  wsc    = (float*)(ws + 184623104);

  prep_kernel<<<9216, 256, 0, stream>>>(x, qx, invs_x, w1, w2, part);
  wscale_final<<<1, 256, 0, stream>>>(part, wsc);
  quant_w_kernel<<<4096, 256, 0, stream>>>(w1, w1q, w2, w2q, wsc);
  gemm_i8<0><<<1024, 1024, 0, stream>>>(qx, w1q, 8192, 2048, 2048, 2048, 32,
                                        invs_x, wsc, 1, (void*)h);
  quant_h_kernel<<<8192, 256, 0, stream>>>(h, invs_h);
  gemm_i8<1><<<256, 1024, 0, stream>>>((const char*)h, w2q, 2048, 8192, 16384, 8192, 8,
                                       invs_h, wsc, 3, d_out);
}

// Round 22
// 405.095 us; speedup vs baseline: 7.3335x; 7.3335x over previous
//
#include <hip/hip_runtime.h>
#include <hip/hip_bf16.h>
#include <hip/hip_fp16.h>

typedef __attribute__((ext_vector_type(4))) int i32x4;
typedef __attribute__((ext_vector_type(8))) unsigned short u16x8;
typedef __attribute__((ext_vector_type(8))) char c8;
typedef __attribute__((ext_vector_type(4))) char c4;
typedef unsigned int u32;
typedef unsigned short u16;

#define SCH0() __builtin_amdgcn_sched_barrier(0)

// ---------- helpers ----------
__device__ __forceinline__ void gload_lds16(const void* g, void* l) {
  __builtin_amdgcn_global_load_lds((const u32 __attribute__((address_space(1)))*)g,
                                   (u32 __attribute__((address_space(3)))*)l, 16, 0, 0);
}
__device__ __forceinline__ float h2f(u16 u) { return __half2float(__ushort_as_half(u)); }
__device__ __forceinline__ u16  f2h(float f){ return __half_as_ushort(__float2half_rn(f)); }

// ---------- 1. FUSED prep: quant_x (blocks 0..8191) + absum w1 (8192..8703) + absum w2 (8704..9215) ----------
__global__ __launch_bounds__(256) void prep_kernel(const float* __restrict__ x,
    char* __restrict__ qx, float* __restrict__ invs,
    const float* __restrict__ w1, const float* __restrict__ w2,
    double* __restrict__ part) {
  const int tid = threadIdx.x;
  __shared__ double sd[256];
  __shared__ float sf[256];
  if (blockIdx.x < 8192) {
    const int D = 2048;
    int row = blockIdx.x;
    const float* xr = x + (size_t)row * D;
    float4 a = ((const float4*)xr)[tid * 2], b = ((const float4*)xr)[tid * 2 + 1];
    float v[8] = {a.x, a.y, a.z, a.w, b.x, b.y, b.z, b.w};
    double ss = 0; float mx = 0.0f;
#pragma unroll
    for (int i = 0; i < 8; i++) { ss += (double)v[i] * v[i]; mx = fmaxf(mx, fabsf(v[i])); }
    sd[tid] = ss; sf[tid] = mx; __syncthreads();
    for (int o = 128; o > 0; o >>= 1) {
      if (tid < o) { sd[tid] += sd[tid + o]; sf[tid] = fmaxf(sf[tid], sf[tid + o]); }
      __syncthreads();
    }
    __shared__ float bn, bs;
    if (tid == 0) {
      float n = fmaxf((float)sqrt(sd[0]), 1e-12f);
      float amax = sf[0] * (sqrtf((float)D) / n);
      float cl = fmaxf(amax, 1e-5f);
      bn = n; bs = 127.0f / cl;
      invs[row] = cl / 127.0f;
    }
    __syncthreads();
    float n = bn, s = bs, sq = sqrtf((float)D);
    c8 q;
#pragma unroll
    for (int i = 0; i < 8; i++) {
      float xn = (v[i] / n) * sq;
      float r = rintf(xn * s);
      r = fminf(fmaxf(r, -128.0f), 127.0f);
      q[i] = (char)(int)r;
    }
    *(c8*)&qx[(size_t)row * D + tid * 8] = q;
  } else {
    const int n4 = 4194304;
    const bool isw2 = blockIdx.x >= 8704;
    const float* w = isw2 ? w2 : w1;
    const int vb = blockIdx.x - (isw2 ? 8704 : 8192);
    double s = 0;
    for (int i = vb * 256 + tid; i < n4; i += 512 * 256) {
      float4 v = ((const float4*)w)[i];
      s += (double)fabsf(v.x) + (double)fabsf(v.y) + (double)fabsf(v.z) + (double)fabsf(v.w);
    }
    sd[tid] = s; __syncthreads();
    for (int o = 128; o > 0; o >>= 1) { if (tid < o) sd[tid] += sd[tid + o]; __syncthreads(); }
    if (tid == 0) part[(isw2 ? 512 : 0) + vb] = sd[0];
  }
}

__global__ __launch_bounds__(256) void wscale_final(const double* __restrict__ part,
    float* __restrict__ wsc) {
  int tid = threadIdx.x;
  __shared__ double sd[256];
  sd[tid] = part[tid] + part[tid + 256]; __syncthreads();
  for (int o = 128; o > 0; o >>= 1) { if (tid < o) sd[tid] += sd[tid + o]; __syncthreads(); }
  double s1 = sd[0]; __syncthreads();
  sd[tid] = part[512 + tid] + part[768 + tid]; __syncthreads();
  for (int o = 128; o > 0; o >>= 1) { if (tid < o) sd[tid] += sd[tid + o]; __syncthreads(); }
  if (tid == 0) {
    float m1 = (float)(s1 / 16777216.0);
    float m2 = (float)(sd[0] / 16777216.0);
    float d1 = fmaxf(m1, 1e-5f), d2 = fmaxf(m2, 1e-5f);
    wsc[0] = 1.0f / d1; wsc[1] = d1; wsc[2] = 1.0f / d2; wsc[3] = d2;
  }
}

// ---------- 2. FUSED ternary weight quant ----------
__global__ __launch_bounds__(256) void quant_w_kernel(const float* __restrict__ w1,
    char* __restrict__ q1, const float* __restrict__ w2, char* __restrict__ q2,
    const float* __restrict__ wsc) {
  const int n4 = 4194304;
  const bool isw2 = blockIdx.x >= 2048;
  const float* w = isw2 ? w2 : w1;
  char* q = isw2 ? q2 : q1;
  float s = isw2 ? wsc[2] : wsc[0];
  const int vb = blockIdx.x - (isw2 ? 2048 : 0);
  for (int i = vb * 256 + threadIdx.x; i < n4; i += 2048 * 256) {
    float4 v = ((const float4*)w)[i];
    c4 o;
    o[0] = (char)(int)(fminf(fmaxf(rintf(v.x * s), -1.0f), 1.0f));
    o[1] = (char)(int)(fminf(fmaxf(rintf(v.y * s), -1.0f), 1.0f));
    o[2] = (char)(int)(fminf(fmaxf(rintf(v.z * s), -1.0f), 1.0f));
    o[3] = (char)(int)(fminf(fmaxf(rintf(v.w * s), -1.0f), 1.0f));
    ((c4*)q)[i] = o;
  }
}

// ---------- 3. 256x256 i8 GEMM, 1024 threads / 16 waves (4 waves/SIMD TLP) — r20 best ----------
// Tile 256x256, BK=64, 3-buffer/96 KiB, stage-2-ahead counted ledger (vmcnt(2)),
// serpentine+XCD raster. Wave grid 4x4, per-wave 64x64: 8 ds_read_b128 + 16 MFMA
// per wave per tile; 4 waves/SIMD hide read latency + barrier skew.
// NOTE: register footprint ~124 (64 AGPR acc + ~60 VGPR) -> 4 waves/SIMD is the
// occupancy ceiling; __launch_bounds__(1024, 8) spills acc to scratch (r21: 7.3x).
#define READ_A4(BUF)                                                       \
  { _Pragma("unroll") for (int f_ = 0; f_ < 4; f_++)                       \
      a[f_] = *(const i32x4*)&sm[BUF][0][(wm * 64 + f_ * 16 + llo) * 64 + koff]; }
#define READ_B4(BUF)                                                       \
  { _Pragma("unroll") for (int f_ = 0; f_ < 4; f_++)                       \
      b[f_] = *(const i32x4*)&sm[BUF][1][(wn * 64 + f_ * 16 + llo) * 64 + koff]; }
#define MMAQ16()                                                           \
  { _Pragma("unroll") for (int m_ = 0; m_ < 4; m_++)                       \
      _Pragma("unroll") for (int n_ = 0; n_ < 4; n_++)                     \
        acc[m_][n_] = __builtin_amdgcn_mfma_i32_16x16x64_i8(a[m_], b[n_],  \
                                                            acc[m_][n_], 0, 0, 0); }
#define STAGE4(BUF, KT)                                                    \
  { size_t ko_ = (size_t)(KT) * 64;                                        \
    gload_lds16(gA + ko_, &sm[BUF][0][tid * 16]);                          \
    gload_lds16(gB + ko_, &sm[BUF][1][tid * 16]); }
#define TILE4(BR, BS, KT)                                                  \
  { STAGE4(BS, (KT) + 2);                                                  \
    SCH0();                                                                \
    READ_A4(BR); READ_B4(BR);                                              \
    MMAQ16();                                                              \
    SCH0();                                                                \
    asm volatile("s_waitcnt vmcnt(2) lgkmcnt(0)\n\ts_barrier" ::: "memory"); }

// EPI==0: dequant + exact GELU -> f16 store.  EPI==1: dequant -> f32 store.
template <int EPI>
__global__ __launch_bounds__(1024, 4) void gemm_i8(const char* __restrict__ A,
    const char* __restrict__ B, int N, int K, size_t ldA, size_t ldB, int gridN,
    const float* __restrict__ rowscale, const float* __restrict__ wsc,
    int widx, void* __restrict__ outp) {
  __shared__ __align__(16) char sm[3][2][16384];   // [buf][mat][256 rows x 64 B] = 96 KiB
  const int tid = threadIdx.x;
  const int lane = tid & 63, w = tid >> 6;
  const int wm = w >> 2, wn = w & 3;               // 4M x 4N wave grid, per-wave 64x64
  const int llo = lane & 15, lhi = lane >> 4;
  const int koff = ((lhi ^ ((llo >> 1) & 3)) << 4); // read-side swizzle key (row>>1)&3

  // T1: bijective XCD swizzle + group-4-row serpentine
  const int nwg = gridDim.x, cpx = nwg >> 3;
  const int swz = (blockIdx.x & 7) * cpx + (blockIdx.x >> 3);
  const int band = gridN << 2;
  const int g = swz / band, idx = swz % band;
  const int bm = (g << 2) + (idx & 3), bn = idx >> 2;

  const int NT = K >> 6;                           // 32 or 128; NT % 3 == 2
  const int NITER = (NT - 2) / 3;

  // staging: thread covers one 16B slot per mat per tile (1024 slots = 256 rows x 64 B)
  // row = tid>>2, kb = tid&3; source kb' = kb ^ ((row>>1)&3) = kb ^ ((tid>>3)&3)
  const int rs = tid >> 2;
  const int kbs = (((tid & 3) ^ ((tid >> 3) & 3)) << 4);
  const char* gA = A + (size_t)(bm * 256 + rs) * ldA + kbs;
  const char* gB = B + (size_t)(bn * 256 + rs) * ldB + kbs;

  i32x4 a[4], b[4];
  i32x4 acc[4][4];
#pragma unroll
  for (int m = 0; m < 4; m++)
#pragma unroll
    for (int n = 0; n < 4; n++) acc[m][n] = (i32x4){0, 0, 0, 0};

  // prologue: t0 -> buf0, fence, t1 -> buf1; retire t0 whole (vmcnt(2) = stage(t1) in flight)
  STAGE4(0, 0);
  asm volatile("s_nop 0" ::: "memory");            // batch boundary fence
  STAGE4(1, 1);
  asm volatile("s_waitcnt vmcnt(2)\n\ts_barrier" ::: "memory");   // tile0 resident

  for (int it = 0, t = 0; it < NITER; ++it, t += 3) {
    TILE4(0, 2, t);
    TILE4(1, 0, t + 1);
    TILE4(2, 1, t + 2);
  }
  // tail t = NT-2 (buf0): no stage; drain everything at the barrier
  {
    READ_A4(0); READ_B4(0);
    MMAQ16();
    SCH0();
    asm volatile("s_waitcnt vmcnt(0) lgkmcnt(0)\n\ts_barrier" ::: "memory");
  }
  // tail t = NT-1 (buf1): no stage, no sync
  {
    READ_A4(1); READ_B4(1);
    MMAQ16();
  }

  // ---- epilogue (i32 -> f32 exact, |acc| << 2^24)
  float wdeq = wsc[widx];
#pragma unroll
  for (int mf = 0; mf < 4; mf++) {
#pragma unroll
    for (int reg = 0; reg < 4; reg++) {
      int r = bm * 256 + wm * 64 + mf * 16 + lhi * 4 + reg;
      float deq = rowscale[r] * wdeq;
#pragma unroll
      for (int nf = 0; nf < 4; nf++) {
        int c = bn * 256 + wn * 64 + nf * 16 + llo;
        float val = (float)acc[mf][nf][reg] * deq;
        if (EPI == 0) {
          float gg = 0.5f * val * (1.0f + erff(val * 0.70710678118654752440f));
          ((u16*)outp)[(size_t)r * N + c] = f2h(gg);
        } else {
          ((float*)outp)[(size_t)r * N + c] = val;
        }
      }
    }
  }
}

// ---------- 4. per-row norm + quant of h: f16 in, i8 out IN-PLACE ----------
__global__ __launch_bounds__(256) void quant_h_kernel(u16* __restrict__ h, float* __restrict__ invs) {
  const int D = 8192;
  int row = blockIdx.x, tid = threadIdx.x;
  u16* hr = h + (size_t)row * D;
  float v[32];
#pragma unroll
  for (int j = 0; j < 4; j++) {
    u16x8 u = *(const u16x8*)&hr[j * 2048 + tid * 8];
#pragma unroll
    for (int e = 0; e < 8; e++) v[j * 8 + e] = h2f(u[e]);
  }
  double ss = 0; float mx = 0.0f;
#pragma unroll
  for (int i = 0; i < 32; i++) { ss += (double)v[i] * v[i]; mx = fmaxf(mx, fabsf(v[i])); }
  __shared__ double sd[256]; __shared__ float sf[256];
  sd[tid] = ss; sf[tid] = mx; __syncthreads();
  for (int o = 128; o > 0; o >>= 1) {
    if (tid < o) { sd[tid] += sd[tid + o]; sf[tid] = fmaxf(sf[tid], sf[tid + o]); }
    __syncthreads();
  }
  __shared__ float bn, bs;
  if (tid == 0) {
    float n = fmaxf((float)sqrt(sd[0]), 1e-12f);
    float amax = sf[0] * (sqrtf((float)D) / n);
    float cl = fmaxf(amax, 1e-5f);
    bn = n; bs = 127.0f / cl;
    invs[row] = cl / 127.0f;
  }
  __syncthreads();
  float n = bn, s = bs, sq = sqrtf((float)D);
  char* hq = (char*)hr;
#pragma unroll
  for (int j = 0; j < 4; j++) {
    c8 q;
#pragma unroll
    for (int e = 0; e < 8; e++) {
      float xn = (v[j * 8 + e] / n) * sq;
      float r = rintf(xn * s);
      r = fminf(fmaxf(r, -128.0f), 127.0f);
      q[e] = (char)(int)r;
    }
    *(c8*)&hq[j * 2048 + tid * 8] = q;
  }
}

// ---------- launch ----------
extern "C" void kernel_launch(void* const* d_in, const int* in_sizes, int n_in,
                              void* d_out, int out_size, void* d_ws, size_t ws_size,
                              hipStream_t stream) {
  const float* x  = (const float*)d_in[0];   // [4,2048,2048] f32
  const float* w1 = (const float*)d_in[1];   // [8192,2048]   f32
  const float* w2 = (const float*)d_in[2];   // [2048,8192]   f32

  char* ws = (char*)d_ws;
  char*   qx     = (char*)(ws + 0);            // 8192x2048 i8
  char*   w1q    = (char*)(ws + 16777216);     // 8192x2048 i8
  char*   w2q    = (char*)(ws + 33554432);     // 2048x8192 i8
  u16*    h      = (u16*)(ws + 50331648);      // 8192x8192 f16; i8 in-place after quant
  float*  invs_x = (float*)(ws + 184549376);
  float*  invs_h = (float*)(ws + 184582144);
  double* part   = (double*)(ws + 184614912);
  float*  wsc    = (float*)(ws + 184623104);

  prep_kernel<<<9216, 256, 0, stream>>>(x, qx, invs_x, w1, w2, part);
  wscale_final<<<1, 256, 0, stream>>>(part, wsc);
  quant_w_kernel<<<4096, 256, 0, stream>>>(w1, w1q, w2, w2q, wsc);
  gemm_i8<0><<<1024, 1024, 0, stream>>>(qx, w1q, 8192, 2048, 2048, 2048, 32,
                                        invs_x, wsc, 1, (void*)h);
  quant_h_kernel<<<8192, 256, 0, stream>>>(h, invs_h);
  gemm_i8<1><<<256, 1024, 0, stream>>>((const char*)h, w2q, 2048, 8192, 16384, 8192, 8,
                                       invs_h, wsc, 3, d_out);
}